// Round 1
// baseline (265.278 us; speedup 1.0000x reference)
//
#include <hip/hip_runtime.h>
#include <stdint.h>

// Per-row top-K magnitude masking.
// x: (rows=4096, NCOLS=8192) fp32. K = round(0.1*8192) = 819.
// One 256-thread block per row; row lives entirely in registers (32 floats/thread).
// Exact 4x8-bit radix select on abs bit patterns (unsigned order == float order for
// non-negative IEEE), per-wave privatized LDS histograms, then masked writeback.

constexpr int NCOLS = 8192;
constexpr int TPB   = 256;
constexpr int V4    = NCOLS / 4;   // 2048 uint4 per row
constexpr int VPT   = V4 / TPB;    // 8 uint4 per thread
constexpr int NH    = 257;         // padded histogram stride (bank-decorrelate copies)

__global__ __launch_bounds__(TPB) void topk_row_kernel(const float* __restrict__ x,
                                                       float* __restrict__ out,
                                                       int K) {
  __shared__ uint32_t hist[4 * NH];
  __shared__ uint32_t sh_digit, sh_rem;

  const int row  = blockIdx.x;
  const int tid  = threadIdx.x;
  const int wave = tid >> 6;

  const uint4* xr = (const uint4*)(x) + (size_t)row * V4;

  // Whole row in registers: 8 x uint4 per thread.
  uint4 v[VPT];
#pragma unroll
  for (int i = 0; i < VPT; ++i) v[i] = xr[tid + i * TPB];

  uint32_t prefix = 0, maskHi = 0, rem = (uint32_t)K;

  for (int pass = 0; pass < 4; ++pass) {
    const int shift = 24 - 8 * pass;

    for (int i = tid; i < 4 * NH; i += TPB) hist[i] = 0;
    __syncthreads();

    uint32_t* h = &hist[wave * NH];
#pragma unroll
    for (int i = 0; i < VPT; ++i) {
      uint32_t a0 = v[i].x & 0x7fffffffu;
      uint32_t a1 = v[i].y & 0x7fffffffu;
      uint32_t a2 = v[i].z & 0x7fffffffu;
      uint32_t a3 = v[i].w & 0x7fffffffu;
      if ((a0 & maskHi) == prefix) atomicAdd(&h[(a0 >> shift) & 255u], 1u);
      if ((a1 & maskHi) == prefix) atomicAdd(&h[(a1 >> shift) & 255u], 1u);
      if ((a2 & maskHi) == prefix) atomicAdd(&h[(a2 >> shift) & 255u], 1u);
      if ((a3 & maskHi) == prefix) atomicAdd(&h[(a3 >> shift) & 255u], 1u);
    }
    __syncthreads();

    // Combine the 4 wave-private copies, then in-place suffix scan over 256 bins.
    uint32_t c = hist[tid] + hist[NH + tid] + hist[2 * NH + tid] + hist[3 * NH + tid];
    __syncthreads();
    hist[tid] = c;
    __syncthreads();
    for (int off = 1; off < 256; off <<= 1) {
      uint32_t add = (tid + off < 256) ? hist[tid + off] : 0u;
      __syncthreads();
      hist[tid] += add;
      __syncthreads();
    }
    // hist[t] = count of candidates with digit >= t. Find bin holding rank `rem`.
    uint32_t sD  = hist[tid];
    uint32_t sD1 = (tid < 255) ? hist[tid + 1] : 0u;
    if (sD >= rem && sD1 < rem) {
      sh_digit = (uint32_t)tid;
      sh_rem   = rem - sD1;
    }
    __syncthreads();
    prefix |= sh_digit << shift;
    maskHi |= 0xFFu << shift;
    rem = sh_rem;
    __syncthreads();  // protect sh_*/hist before next pass's zeroing
  }

  // prefix is now the exact bit pattern of the K-th largest |x| in this row.
  const uint32_t thr = prefix;
  uint4* outr = (uint4*)(out) + (size_t)row * V4;
#pragma unroll
  for (int i = 0; i < VPT; ++i) {
    uint4 o = v[i];
    o.x = ((o.x & 0x7fffffffu) >= thr) ? o.x : 0u;
    o.y = ((o.y & 0x7fffffffu) >= thr) ? o.y : 0u;
    o.z = ((o.z & 0x7fffffffu) >= thr) ? o.z : 0u;
    o.w = ((o.w & 0x7fffffffu) >= thr) ? o.w : 0u;
    outr[tid + i * TPB] = o;
  }
}

extern "C" void kernel_launch(void* const* d_in, const int* in_sizes, int n_in,
                              void* d_out, int out_size, void* d_ws, size_t ws_size,
                              hipStream_t stream) {
  (void)n_in; (void)out_size; (void)d_ws; (void)ws_size;
  const float* x = (const float*)d_in[0];
  float* out = (float*)d_out;
  const int rows = in_sizes[0] / NCOLS;
  const int K = (int)(0.1 * NCOLS + 0.5);  // round(819.2) = 819
  topk_row_kernel<<<rows, TPB, 0, stream>>>(x, out, K);
}

// Round 2
// 231.453 us; speedup vs baseline: 1.1461x; 1.1461x over previous
//
#include <hip/hip_runtime.h>
#include <stdint.h>

// Per-row top-K magnitude masking, exact.
// x: (4096 rows, 8192 cols) fp32. K = 819. One 256-thread block per row, row
// held in registers (8 x uint4 / thread). Exact radix select on the 31-bit
// abs bit pattern in 3 wide phases: 11 bits (2048 bins), 10 bits, 10 bits.
// Wide phase-1 bins spread the Gaussian exponent clustering across mantissa
// bins (kills LDS same-address atomic serialization); wave-shuffle suffix
// scans cut barriers from ~80/block to 12/block.

constexpr int NCOLS = 8192;
constexpr int TPB   = 256;
constexpr int V4    = NCOLS / 4;   // 2048 uint4 per row
constexpr int VPT   = V4 / TPB;    // 8 uint4 per thread

constexpr int PAD = 8;             // words between histogram copies (bank shift)
constexpr int B1 = 2048, C1 = 2;   // phase 1: 11 bits, 2 copies (2 waves/copy)
constexpr int B2 = 1024, C2 = 4;   // phase 2/3: 10 bits, 4 copies (1 wave/copy)
constexpr int S1 = B1 + PAD;       // 2056
constexpr int S2 = B2 + PAD;       // 1032
constexpr int HW = (C2 * S2 > C1 * S1) ? C2 * S2 : C1 * S1;  // 4128 words

struct Shared {
  uint32_t hist[HW];
  uint32_t wavesum[4];
  uint32_t digit;
  uint32_t rem;
};

// One radix-select phase. Candidates: (key >> cshift) == cprefix.
// Digit: (key >> dshift) & (BINS-1). Returns winning digit, updates rem to
// the rank within the winning bin.
template <int BINS, int COPIES>
__device__ __forceinline__ uint32_t run_phase(Shared& sh, const uint4 (&v)[VPT],
                                              int dshift, int cshift, uint32_t cprefix,
                                              uint32_t& rem, int tid, int lane, int wave) {
  constexpr int BPT = BINS / TPB;          // bins per thread (8 or 4)
  constexpr int STRIDE = BINS + PAD;
  constexpr int ZW4 = (COPIES * STRIDE) / 4;

  // Zero the histogram region (vectorized).
  uint4* hz = (uint4*)sh.hist;
  for (int i = tid; i < ZW4; i += TPB) hz[i] = make_uint4(0u, 0u, 0u, 0u);
  __syncthreads();

  // Histogram candidates into this wave's copy.
  uint32_t* h = &sh.hist[((wave * COPIES) >> 2) * STRIDE];
#pragma unroll
  for (int i = 0; i < VPT; ++i) {
    uint32_t a[4] = {v[i].x, v[i].y, v[i].z, v[i].w};
#pragma unroll
    for (int j = 0; j < 4; ++j) {
      uint32_t key = a[j] & 0x7fffffffu;
      if ((key >> cshift) == cprefix)
        atomicAdd(&h[(key >> dshift) & (BINS - 1)], 1u);
    }
  }
  __syncthreads();

  // Combine copies; per-thread bin counts hb[] over bins [tid*BPT, tid*BPT+BPT).
  uint32_t hb[BPT];
#pragma unroll
  for (int j = 0; j < BPT; ++j) hb[j] = 0;
#pragma unroll
  for (int c = 0; c < COPIES; ++c) {
    const uint4* hp = (const uint4*)&sh.hist[c * STRIDE + tid * BPT];
#pragma unroll
    for (int q = 0; q < BPT / 4; ++q) {
      uint4 t = hp[q];
      hb[4 * q + 0] += t.x; hb[4 * q + 1] += t.y;
      hb[4 * q + 2] += t.z; hb[4 * q + 3] += t.w;
    }
  }
  uint32_t L = 0;
#pragma unroll
  for (int j = 0; j < BPT; ++j) L += hb[j];

  // Wave-level inclusive suffix scan of L (no barriers).
  uint32_t suf = L;
#pragma unroll
  for (int off = 1; off < 64; off <<= 1) {
    uint32_t o = __shfl_down(suf, off, 64);
    suf += (lane + off < 64) ? o : 0u;
  }
  if (lane == 0) sh.wavesum[wave] = suf;   // wave total
  __syncthreads();
  uint32_t addw = 0;
#pragma unroll
  for (int w = 0; w < 4; ++w) addw += (w > wave) ? sh.wavesum[w] : 0u;
  suf += addw;  // suffix count starting at this thread's first bin

  // Walk own bins high->low. S(b) = #candidates with digit >= b.
  // Winner: S(b) >= rem && S(b+1) < rem (unique).
  uint32_t s = suf - L;                    // S at bin (tid+1)*BPT
#pragma unroll
  for (int j = BPT - 1; j >= 0; --j) {
    uint32_t snext = s;                    // S(bin+1)
    s += hb[j];                            // S(bin)
    if (s >= rem && snext < rem) {
      sh.digit = (uint32_t)(tid * BPT + j);
      sh.rem = rem - snext;
    }
  }
  __syncthreads();
  uint32_t d = sh.digit;
  rem = sh.rem;
  // No trailing barrier needed: next phase's first barrier (after zeroing)
  // orders these reads before any write to sh.digit/sh.rem/wavesum, and the
  // zeroing only touches hist[], whose reads completed before the wavesum
  // barrier above.
  return d;
}

__global__ __launch_bounds__(TPB) void topk_row_kernel(const float* __restrict__ x,
                                                       float* __restrict__ out,
                                                       int K) {
  __shared__ Shared sh;
  const int row  = blockIdx.x;
  const int tid  = threadIdx.x;
  const int lane = tid & 63;
  const int wave = tid >> 6;

  const uint4* xr = (const uint4*)(x) + (size_t)row * V4;
  uint4 v[VPT];
#pragma unroll
  for (int i = 0; i < VPT; ++i) v[i] = xr[tid + i * TPB];

  uint32_t rem = (uint32_t)K;
  uint32_t d1 = run_phase<B1, C1>(sh, v, 20, 31, 0u, rem, tid, lane, wave);
  uint32_t d2 = run_phase<B2, C2>(sh, v, 10, 20, d1, rem, tid, lane, wave);
  uint32_t d3 = run_phase<B2, C2>(sh, v,  0, 10, (d1 << 10) | d2, rem, tid, lane, wave);

  const uint32_t thr = (d1 << 20) | (d2 << 10) | d3;  // exact K-th largest |x| bits

  uint4* outr = (uint4*)(out) + (size_t)row * V4;
#pragma unroll
  for (int i = 0; i < VPT; ++i) {
    uint4 o = v[i];
    o.x = ((o.x & 0x7fffffffu) >= thr) ? o.x : 0u;
    o.y = ((o.y & 0x7fffffffu) >= thr) ? o.y : 0u;
    o.z = ((o.z & 0x7fffffffu) >= thr) ? o.z : 0u;
    o.w = ((o.w & 0x7fffffffu) >= thr) ? o.w : 0u;
    outr[tid + i * TPB] = o;
  }
}

extern "C" void kernel_launch(void* const* d_in, const int* in_sizes, int n_in,
                              void* d_out, int out_size, void* d_ws, size_t ws_size,
                              hipStream_t stream) {
  (void)n_in; (void)out_size; (void)d_ws; (void)ws_size;
  const float* x = (const float*)d_in[0];
  float* out = (float*)d_out;
  const int rows = in_sizes[0] / NCOLS;
  const int K = (int)(0.1 * NCOLS + 0.5);  // round(819.2) = 819
  topk_row_kernel<<<rows, TPB, 0, stream>>>(x, out, K);
}